// Round 4
// baseline (16.843 us; speedup 1.0000x reference)
//
#include <hip/hip_runtime.h>

// DecorrelationPatch2d, fused single kernel, one block per (n,c) plane.
// out[n,c,y,x] = x[n,c,y,x] * ( sum_{valid i,j} s[c*9+3i+j] ) / (ny*nx)
//   s[k] = sum_m R[k,m];  valid i: max(0,y-125) <= i <= min(2,y)  (H=128, KH=3)
// 512 blocks x 512 threads; each block computes its channel's 9 R-row-sums
// (float4 loads, wave-per-row shuffle reduce; R is L2-resident) while its
// 8 x-loads/thread are in flight, then scales + stores.

#define PL 576   // patch length = 64*3*3

__global__ __launch_bounds__(512) void decor_fused(const float* __restrict__ x,
                                                   const float* __restrict__ R,
                                                   float* __restrict__ out) {
    __shared__ float s9[9];
    const int tid   = threadIdx.x;        // 0..511
    const int b     = blockIdx.x;         // 0..511 == plane (n*64 + c)
    const int c     = b & 63;
    const int base4 = b * 4096;           // float4 index of plane start

    // ---- issue the 8 independent x-loads first (hide HBM latency under the
    //      R reduction) ----
    const float4* __restrict__ x4p = reinterpret_cast<const float4*>(x);
    float4 v0 = x4p[base4 + 0 * 512 + tid];
    float4 v1 = x4p[base4 + 1 * 512 + tid];
    float4 v2 = x4p[base4 + 2 * 512 + tid];
    float4 v3 = x4p[base4 + 3 * 512 + tid];
    float4 v4 = x4p[base4 + 4 * 512 + tid];
    float4 v5 = x4p[base4 + 5 * 512 + tid];
    float4 v6 = x4p[base4 + 6 * 512 + tid];
    float4 v7 = x4p[base4 + 7 * 512 + tid];

    // ---- phase 1: s9[r] = sum of R[c*9+r, :]  (wave r does row r; wave 0
    //      also row 8; float4 loads: 144 f4/row over 64 lanes) ----
    const int wave = tid >> 6, lane = tid & 63;
    for (int r = wave; r < 9; r += 8) {
        const float4* __restrict__ row4 =
            reinterpret_cast<const float4*>(R + (c * 9 + r) * PL);
        float4 p = row4[lane];
        float4 q = row4[lane + 64];
        float acc = (p.x + p.y) + (p.z + p.w) + (q.x + q.y) + (q.z + q.w);
        if (lane < 16) {
            float4 u = row4[lane + 128];
            acc += (u.x + u.y) + (u.z + u.w);
        }
        #pragma unroll
        for (int off = 32; off > 0; off >>= 1) acc += __shfl_down(acc, off, 64);
        if (lane == 0) s9[r] = acc;
    }
    __syncthreads();

    const float a0 = s9[0], a1 = s9[1], a2 = s9[2];
    const float a3 = s9[3], a4 = s9[4], a5 = s9[5];
    const float a6 = s9[6], a7 = s9[7], a8 = s9[8];

    // ---- per-element x (column) predicates: constant across iterations ----
    const int x4i = tid & 31;
    float jw0[4], jw1[4], jw2[4], invnx[4];   // fully unrolled -> registers
    #pragma unroll
    for (int e = 0; e < 4; ++e) {
        const int xx = x4i * 4 + e;
        const bool j0 = (xx <= 125);
        const bool j1 = (xx >= 1) && (xx <= 126);
        const bool j2 = (xx >= 2);
        jw0[e] = j0 ? 1.f : 0.f;
        jw1[e] = j1 ? 1.f : 0.f;
        jw2[e] = j2 ? 1.f : 0.f;
        const int nx = (int)j0 + (int)j1 + (int)j2;
        invnx[e] = (nx == 3) ? (1.f / 3.f) : ((nx == 2) ? 0.5f : 1.f);
    }

    // ---- phase 2: scale + store; y = k*16 + tid/32 ----
    const int yb = tid >> 5;
    float4* __restrict__ o4p = reinterpret_cast<float4*>(out);
    float4 vv[8] = {v0, v1, v2, v3, v4, v5, v6, v7};
    #pragma unroll
    for (int k = 0; k < 8; ++k) {
        const int y = k * 16 + yb;
        const bool i0 = (y <= 125);
        const bool i1 = (y >= 1) && (y <= 126);
        const bool i2 = (y >= 2);
        const int ny = (int)i0 + (int)i1 + (int)i2;
        const float invny = (ny == 3) ? (1.f / 3.f) : ((ny == 2) ? 0.5f : 1.f);
        const float f0 = ((i0 ? a0 : 0.f) + (i1 ? a3 : 0.f) + (i2 ? a6 : 0.f)) * invny;
        const float f1 = ((i0 ? a1 : 0.f) + (i1 ? a4 : 0.f) + (i2 ? a7 : 0.f)) * invny;
        const float f2 = ((i0 ? a2 : 0.f) + (i1 ? a5 : 0.f) + (i2 ? a8 : 0.f)) * invny;

        float r[4] = {vv[k].x, vv[k].y, vv[k].z, vv[k].w};
        #pragma unroll
        for (int e = 0; e < 4; ++e) {
            const float factor = (jw0[e] * f0 + jw1[e] * f1 + jw2[e] * f2) * invnx[e];
            r[e] *= factor;
        }
        float4 o;
        o.x = r[0]; o.y = r[1]; o.z = r[2]; o.w = r[3];
        o4p[base4 + k * 512 + tid] = o;
    }
}

extern "C" void kernel_launch(void* const* d_in, const int* in_sizes, int n_in,
                              void* d_out, int out_size, void* d_ws, size_t ws_size,
                              hipStream_t stream) {
    const float* x = (const float*)d_in[0];   // [8,64,128,128] fp32
    const float* R = (const float*)d_in[1];   // [576,576] fp32
    float* out = (float*)d_out;               // [8,64,128,128] fp32
    (void)d_ws; (void)ws_size;

    decor_fused<<<512, 512, 0, stream>>>(x, R, out);
}

// Round 6
// 15.126 us; speedup vs baseline: 1.1135x; 1.1135x over previous
//
#include <hip/hip_runtime.h>

// DecorrelationPatch2d, fused single kernel, one block per (n,c) plane.
// out[n,c,y,x] = x[n,c,y,x] * ( sum_{valid i,j} s[c*9+3i+j] ) / (ny*nx)
//   s[k] = sum_m R[k,m];  valid i: max(0,y-125) <= i <= min(2,y)  (H=128, KH=3)
// Key ordering: R-row loads are issued BEFORE the x stream loads. Per-wave
// loads return in order, so this way the 9-row reduce completes after ~L2
// latency and each store k can issue as soon as x-load k returns (read/write
// overlap); issuing x first would gate the prologue on the wave's entire
// 64 KB read stream (two serialized phases).

#define PL 576   // patch length = 64*3*3

// native vector type: required by __builtin_nontemporal_{load,store}
typedef float f32x4 __attribute__((ext_vector_type(4)));

__global__ __launch_bounds__(512) void decor_fused(const float* __restrict__ x,
                                                   const float* __restrict__ R,
                                                   float* __restrict__ out) {
    __shared__ float s9[9];
    const int tid   = threadIdx.x;        // 0..511
    const int b     = blockIdx.x;         // 0..511 == plane (n*64 + c)
    const int c     = b & 63;
    const int base4 = b * 4096;           // float4 index of plane start
    const int wave  = tid >> 6, lane = tid & 63;

    // ---- issue R loads FIRST (return early, in-order, from L2) ----
    // wave w reduces row w; wave 0 additionally row 8 (both prefetched).
    const f32x4* __restrict__ rowA =
        reinterpret_cast<const f32x4*>(R + (c * 9 + wave) * PL);
    const f32x4 p0 = rowA[lane];
    const f32x4 p1 = rowA[lane + 64];
    const f32x4 p2 = rowA[(lane & 15) + 128];           // masked below
    const float m2 = (lane < 16) ? 1.f : 0.f;

    f32x4 q0 = 0.f, q1 = 0.f, q2 = 0.f;
    if (wave == 0) {                                    // wave-uniform branch
        const f32x4* __restrict__ rowB =
            reinterpret_cast<const f32x4*>(R + (c * 9 + 8) * PL);
        q0 = rowB[lane];
        q1 = rowB[lane + 64];
        q2 = rowB[(lane & 15) + 128];
    }

    // ---- then the 8 independent x stream loads (nontemporal) ----
    const f32x4* __restrict__ x4p = reinterpret_cast<const f32x4*>(x);
    f32x4 v0 = __builtin_nontemporal_load(&x4p[base4 + 0 * 512 + tid]);
    f32x4 v1 = __builtin_nontemporal_load(&x4p[base4 + 1 * 512 + tid]);
    f32x4 v2 = __builtin_nontemporal_load(&x4p[base4 + 2 * 512 + tid]);
    f32x4 v3 = __builtin_nontemporal_load(&x4p[base4 + 3 * 512 + tid]);
    f32x4 v4 = __builtin_nontemporal_load(&x4p[base4 + 4 * 512 + tid]);
    f32x4 v5 = __builtin_nontemporal_load(&x4p[base4 + 5 * 512 + tid]);
    f32x4 v6 = __builtin_nontemporal_load(&x4p[base4 + 6 * 512 + tid]);
    f32x4 v7 = __builtin_nontemporal_load(&x4p[base4 + 7 * 512 + tid]);

    // ---- reduce the R rows (waits only on the early R loads) ----
    {
        float acc = (p0.x + p0.y) + (p0.z + p0.w)
                  + (p1.x + p1.y) + (p1.z + p1.w)
                  + m2 * ((p2.x + p2.y) + (p2.z + p2.w));
        float accB = 0.f;
        if (wave == 0)
            accB = (q0.x + q0.y) + (q0.z + q0.w)
                 + (q1.x + q1.y) + (q1.z + q1.w)
                 + m2 * ((q2.x + q2.y) + (q2.z + q2.w));
        #pragma unroll
        for (int off = 32; off > 0; off >>= 1) {
            acc  += __shfl_down(acc,  off, 64);
            accB += __shfl_down(accB, off, 64);
        }
        if (lane == 0) {
            s9[wave] = acc;
            if (wave == 0) s9[8] = accB;
        }
    }
    __syncthreads();

    const float a0 = s9[0], a1 = s9[1], a2 = s9[2];
    const float a3 = s9[3], a4 = s9[4], a5 = s9[5];
    const float a6 = s9[6], a7 = s9[7], a8 = s9[8];

    // ---- per-element x (column) predicates: constant across iterations ----
    const int x4i = tid & 31;
    float jw0[4], jw1[4], jw2[4], invnx[4];   // fully unrolled -> registers
    #pragma unroll
    for (int e = 0; e < 4; ++e) {
        const int xx = x4i * 4 + e;
        const bool j0 = (xx <= 125);
        const bool j1 = (xx >= 1) && (xx <= 126);
        const bool j2 = (xx >= 2);
        jw0[e] = j0 ? 1.f : 0.f;
        jw1[e] = j1 ? 1.f : 0.f;
        jw2[e] = j2 ? 1.f : 0.f;
        const int nx = (int)j0 + (int)j1 + (int)j2;
        invnx[e] = (nx == 3) ? (1.f / 3.f) : ((nx == 2) ? 0.5f : 1.f);
    }

    // ---- scale + store (nontemporal); y = k*16 + tid/32 ----
    const int yb = tid >> 5;
    f32x4* __restrict__ o4p = reinterpret_cast<f32x4*>(out);
    f32x4 vv[8] = {v0, v1, v2, v3, v4, v5, v6, v7};
    #pragma unroll
    for (int k = 0; k < 8; ++k) {
        const int y = k * 16 + yb;
        const bool i0 = (y <= 125);
        const bool i1 = (y >= 1) && (y <= 126);
        const bool i2 = (y >= 2);
        const int ny = (int)i0 + (int)i1 + (int)i2;
        const float invny = (ny == 3) ? (1.f / 3.f) : ((ny == 2) ? 0.5f : 1.f);
        const float f0 = ((i0 ? a0 : 0.f) + (i1 ? a3 : 0.f) + (i2 ? a6 : 0.f)) * invny;
        const float f1 = ((i0 ? a1 : 0.f) + (i1 ? a4 : 0.f) + (i2 ? a7 : 0.f)) * invny;
        const float f2 = ((i0 ? a2 : 0.f) + (i1 ? a5 : 0.f) + (i2 ? a8 : 0.f)) * invny;

        f32x4 o;
        o.x = vv[k].x * ((jw0[0] * f0 + jw1[0] * f1 + jw2[0] * f2) * invnx[0]);
        o.y = vv[k].y * ((jw0[1] * f0 + jw1[1] * f1 + jw2[1] * f2) * invnx[1]);
        o.z = vv[k].z * ((jw0[2] * f0 + jw1[2] * f1 + jw2[2] * f2) * invnx[2]);
        o.w = vv[k].w * ((jw0[3] * f0 + jw1[3] * f1 + jw2[3] * f2) * invnx[3]);
        __builtin_nontemporal_store(o, &o4p[base4 + k * 512 + tid]);
    }
}

extern "C" void kernel_launch(void* const* d_in, const int* in_sizes, int n_in,
                              void* d_out, int out_size, void* d_ws, size_t ws_size,
                              hipStream_t stream) {
    const float* x = (const float*)d_in[0];   // [8,64,128,128] fp32
    const float* R = (const float*)d_in[1];   // [576,576] fp32
    float* out = (float*)d_out;               // [8,64,128,128] fp32
    (void)d_ws; (void)ws_size;

    decor_fused<<<512, 512, 0, stream>>>(x, R, out);
}